// Round 8
// baseline (164.874 us; speedup 1.0000x reference)
//
#include <hip/hip_runtime.h>

#define BATCH 16
#define NBOX  2048
#define NCLS  80
#define ROWF  85
#define CONF_THRF 0.2f
#define NMS_THRF  0.45f
#define CAP   128                 // per-(img,class) candidate/kept cap (tail prob ~1e-40)
#define JOBS  (BATCH*NCLS)        // 1280 per-(img,class) NMS jobs
#define NBLK  256
#define NTHR  1024

// ws layout (bytes)
#define WS_BAR  0                                  // i32[2] grid-barrier state
#define WS_S    64                                 // f32[32768] scores
#define WS_CP   (WS_S  + BATCH*NBOX*4)             // f32[32768] classprob max
#define WS_L    (WS_CP + BATCH*NBOX*4)             // i32[32768] labels
#define WS_KC   (WS_L  + BATCH*NBOX*4)             // u64[1280*CAP] kept keys per (img,class)
#define WS_KCLS (WS_KC + (size_t)JOBS*CAP*8)       // i32[1280] kept counts (always written)

static __device__ inline unsigned long long shflx64(unsigned long long v, int m) {
  int lo = __shfl_xor((int)(unsigned)(v & 0xffffffffull), m, 64);
  int hi = __shfl_xor((int)(unsigned)(v >> 32), m, 64);
  return ((unsigned long long)(unsigned)hi << 32) | (unsigned)lo;
}

// device-scope grid barrier: all NBLK blocks co-resident (256 blocks, <=128 VGPR, 16KB LDS)
static __device__ inline void gridbar(int* bar, int expect) {
  __syncthreads();
  if (threadIdx.x == 0) {
    __threadfence();                                   // flush my stores device-wide
    int old = __hip_atomic_fetch_add(&bar[0], 1, __ATOMIC_ACQ_REL, __HIP_MEMORY_SCOPE_AGENT);
    if (old == NBLK - 1) {
      __hip_atomic_store(&bar[0], 0, __ATOMIC_RELAXED, __HIP_MEMORY_SCOPE_AGENT);
      __hip_atomic_store(&bar[1], expect, __ATOMIC_RELEASE, __HIP_MEMORY_SCOPE_AGENT);
    } else {
      while (__hip_atomic_load(&bar[1], __ATOMIC_ACQUIRE, __HIP_MEMORY_SCOPE_AGENT) < expect)
        __builtin_amdgcn_s_sleep(1);
    }
    __threadfence();                                   // acquire: invalidate stale lines
  }
  __syncthreads();
}

// ---- node 1: re-init barrier state every call (ws is poisoned; replay must be deterministic)
__global__ __launch_bounds__(64) void binit_kernel(int* __restrict__ bar) {
  if (threadIdx.x < 2) bar[threadIdx.x] = 0;
}

// ---- node 2: everything (prep | grid-bar | per-class NMS | grid-bar | sort+write) ----
__global__ __launch_bounds__(1024, 4) void fused_kernel(const float* __restrict__ det,
                                                        float* __restrict__ out,
                                                        float* __restrict__ s_ws,
                                                        float* __restrict__ cp_ws,
                                                        int* __restrict__ l_ws,
                                                        unsigned long long* __restrict__ keptc,
                                                        int* __restrict__ kcls,
                                                        int* __restrict__ bar) {
  __shared__ union {
    unsigned short cand[16][CAP];      // P2: per-wave candidate lists (4 KB)
    unsigned long long key[NBOX];      // P3: 16 KB sort scratch
  } sm;
  __shared__ int offL[NCLS];
  __shared__ int KtotS;

  const int bid = blockIdx.x;
  const int tid = threadIdx.x;
  const int lane = tid & 63, wid = tid >> 6;
  const int sub = lane & 15, grp = lane >> 4;

  // ================= P1: per-row score/argmax + zero out =================
#pragma unroll
  for (int p = 0; p < 2; ++p) {
    int row = bid * 128 + wid * 8 + p * 4 + grp;         // 256 blocks x 128 rows
    const float* r = det + (size_t)row * ROWF;
    float best = r[5 + sub];
    int bc = sub;
#pragma unroll
    for (int k = 1; k < 5; ++k) {
      float v = r[5 + sub + 16 * k];
      if (v > best) { best = v; bc = sub + 16 * k; }     // strict >: first max wins
    }
#pragma unroll
    for (int d = 1; d < 16; d <<= 1) {                   // 16-lane argmax, tie -> min idx
      float ov = __shfl_xor(best, d, 16);
      int oc = __shfl_xor(bc, d, 16);
      if (ov > best || (ov == best && oc < bc)) { best = ov; bc = oc; }
    }
    if (sub == 0) { s_ws[row] = r[4]; cp_ws[row] = best; l_ws[row] = bc; }
  }
  {
    int gid = bid * NTHR + tid;                          // zero 1MB output with first 65536 thr
    if (gid < (BATCH * NBOX * 8) / 4)
      ((float4*)out)[gid] = make_float4(0.f, 0.f, 0.f, 0.f);
  }

  gridbar(bar, 1);

  // ================= P2: per-(img,class) candidate scan + sort + greedy NMS =================
  const int j = bid * 16 + wid;                          // wave-level job id
  if (j < JOBS) {
    const int img = j / NCLS, c = j - img * NCLS;
    const size_t ibase = (size_t)img * NBOX;
    const float* sImg = s_ws + ibase;
    const int* lImg = l_ws + ibase;
    unsigned short* mycand = sm.cand[wid];

    int cnt = 0;
    for (int it = 0; it < 32; ++it) {                    // ballot scan: coalesced, no atomics
      int i = it * 64 + lane;
      bool match = (sImg[i] > CONF_THRF) && (lImg[i] == c);
      unsigned long long mk = __ballot(match);
      if (match) {
        int rk = cnt + __popcll(mk & ((1ull << lane) - 1ull));
        if (rk < CAP) mycand[rk] = (unsigned short)i;
      }
      cnt += __popcll(mk);
    }
    int m = cnt < CAP ? cnt : CAP;

    // keys: (~score_bits)<<32 | idx -> ascending == (score desc, idx asc); pad all-ones
    unsigned long long e0 = ~0ull, e1 = ~0ull;
    if (lane < m) {
      int n = mycand[lane];
      e0 = ((unsigned long long)(~__float_as_uint(sImg[n])) << 32) | (unsigned)n;
    }
    if (lane + 64 < m) {
      int n = mycand[lane + 64];
      e1 = ((unsigned long long)(~__float_as_uint(sImg[n])) << 32) | (unsigned)n;
    }
    const bool two = (m > 64);
    if (!two) {
#pragma unroll
      for (int k = 2; k <= 64; k <<= 1)
        for (int jj = k >> 1; jj > 0; jj >>= 1) {
          bool amLow = (lane & jj) == 0;
          bool up = ((lane & k) == 0);
          unsigned long long o = shflx64(e0, jj);
          e0 = (up == amLow) ? (e0 < o ? e0 : o) : (e0 > o ? e0 : o);
        }
    } else {
#pragma unroll
      for (int k = 2; k <= 128; k <<= 1)
        for (int jj = k >> 1; jj > 0; jj >>= 1) {
          if (jj == 64) {
            bool up = ((lane & k) == 0);
            if (up ? (e0 > e1) : (e0 < e1)) { unsigned long long t = e0; e0 = e1; e1 = t; }
          } else {
            bool amLow = (lane & jj) == 0;
            bool up0 = ((lane & k) == 0), up1 = (((lane + 64) & k) == 0);
            unsigned long long o0 = shflx64(e0, jj), o1 = shflx64(e1, jj);
            e0 = (up0 == amLow) ? (e0 < o0 ? e0 : o0) : (e0 > o0 ? e0 : o0);
            e1 = (up1 == amLow) ? (e1 < o1 ? e1 : o1) : (e1 > o1 ? e1 : o1);
          }
        }
    }

    const float off = (float)c * 10000.0f;
    bool valid0 = lane < m, valid1 = two && (lane + 64 < m);
    int n0 = (int)((unsigned)e0 & (NBOX - 1));
    int n1 = (int)((unsigned)e1 & (NBOX - 1));
    float x1 = 0, y1 = 0, x2 = 0, y2 = 0, ar = 0;
    if (valid0) {
      const float* rr = det + (ibase + n0) * ROWF;
      x1 = rr[0] + off; y1 = rr[1] + off; x2 = rr[2] + off; y2 = rr[3] + off;
      ar = fmaxf(x2 - x1, 0.0f) * fmaxf(y2 - y1, 0.0f);
    }
    float X1 = 0, Y1 = 0, X2 = 0, Y2 = 0, AR = 0;
    if (valid1) {
      const float* rr = det + (ibase + n1) * ROWF;
      X1 = rr[0] + off; Y1 = rr[1] + off; X2 = rr[2] + off; Y2 = rr[3] + off;
      AR = fmaxf(X2 - X1, 0.0f) * fmaxf(Y2 - Y1, 0.0f);
    }

    unsigned long long keptm0 = 0, und = __ballot(valid0);
    while (und) {
      int i = __ffsll((long long)und) - 1;
      keptm0 |= 1ull << i;
      float kx1 = __shfl(x1, i, 64), ky1 = __shfl(y1, i, 64);
      float kx2 = __shfl(x2, i, 64), ky2 = __shfl(y2, i, 64);
      float kar = __shfl(ar, i, 64);
      float iw = fminf(x2, kx2) - fmaxf(x1, kx1);
      float ih = fminf(y2, ky2) - fmaxf(y1, ky1);
      float inter = fmaxf(iw, 0.0f) * fmaxf(ih, 0.0f);
      float iou = inter / (((kar + ar) - inter) + 1e-7f);    // exact ref op order
      bool sup = (lane > i) && (iou > NMS_THRF);
      und &= ~__ballot(sup);
      und &= ~(1ull << i);
    }
    unsigned long long keptm1 = 0;
    if (two) {
      bool dead = false;
      unsigned long long km = keptm0;
      while (km) {
        int t = __ffsll((long long)km) - 1; km &= km - 1;
        float kx1 = __shfl(x1, t, 64), ky1 = __shfl(y1, t, 64);
        float kx2 = __shfl(x2, t, 64), ky2 = __shfl(y2, t, 64);
        float kar = __shfl(ar, t, 64);
        float iw = fminf(X2, kx2) - fmaxf(X1, kx1);
        float ih = fminf(Y2, ky2) - fmaxf(Y1, ky1);
        float inter = fmaxf(iw, 0.0f) * fmaxf(ih, 0.0f);
        float iou = inter / (((kar + AR) - inter) + 1e-7f);
        dead |= (iou > NMS_THRF);
      }
      unsigned long long und1 = __ballot(valid1 && !dead);
      while (und1) {
        int i = __ffsll((long long)und1) - 1;
        keptm1 |= 1ull << i;
        float kx1 = __shfl(X1, i, 64), ky1 = __shfl(Y1, i, 64);
        float kx2 = __shfl(X2, i, 64), ky2 = __shfl(Y2, i, 64);
        float kar = __shfl(AR, i, 64);
        float iw = fminf(X2, kx2) - fmaxf(X1, kx1);
        float ih = fminf(Y2, ky2) - fmaxf(Y1, ky1);
        float inter = fmaxf(iw, 0.0f) * fmaxf(ih, 0.0f);
        float iou = inter / (((kar + AR) - inter) + 1e-7f);
        bool sup = (lane > i) && (iou > NMS_THRF);
        und1 &= ~__ballot(sup);
        und1 &= ~(1ull << i);
      }
    }

    // kept keys to fixed per-class slots (no atomics); count always written
    unsigned long long* dst = keptc + (size_t)j * CAP;
    if ((keptm0 >> lane) & 1) {
      int rank = __popcll(keptm0 & ((1ull << lane) - 1ull));
      dst[rank] = (e0 & 0xffffffff00000000ull) | (unsigned)((n0 << 7) | c);
    }
    if (two && ((keptm1 >> lane) & 1)) {
      int rank = __popcll(keptm0) + __popcll(keptm1 & ((1ull << lane) - 1ull));
      dst[rank] = (e1 & 0xffffffff00000000ull) | (unsigned)((n1 << 7) | c);
    }
    if (lane == 0) kcls[j] = __popcll(keptm0) + __popcll(keptm1);
  }

  gridbar(bar, 2);

  // ================= P3: per-image gather + hybrid sort + row writes (blocks 0..15) =====
  if (bid < BATCH) {
    const int img = bid;
    const size_t ibase = (size_t)img * NBOX;

    for (int t = tid; t < NBOX; t += NTHR) sm.key[t] = ~0ull;
    __syncthreads();

    if (wid == 0) {                                      // 80-wide exclusive scan of kept counts
      int v0 = kcls[img * NCLS + lane];                  // t = 0..63
      int v1 = (lane < NCLS - 64) ? kcls[img * NCLS + 64 + lane] : 0;
      int s0 = v0;
#pragma unroll
      for (int d = 1; d < 64; d <<= 1) { int u = __shfl_up(s0, d, 64); if (lane >= d) s0 += u; }
      int total0 = __shfl(s0, 63, 64);
      int s1 = v1;
#pragma unroll
      for (int d = 1; d < 16; d <<= 1) { int u = __shfl_up(s1, d, 64); if (lane >= d) s1 += u; }
      offL[lane] = s0 - v0;
      if (lane < NCLS - 64) offL[64 + lane] = total0 + s1 - v1;
      if (lane == 15) KtotS = total0 + s1;
    }
    __syncthreads();

    for (int c = wid; c < NCLS; c += 16) {               // gather per-class kept keys
      int kc = kcls[img * NCLS + c];
      const unsigned long long* src = keptc + (size_t)(img * NCLS + c) * CAP;
      int o = offL[c];
      for (int q = lane; q < kc; q += 64) sm.key[o + q] = src[q];
    }
    __syncthreads();

    const int K = KtotS;
    const int i0 = (wid << 7) + lane, i1 = i0 + 64;
    unsigned long long e0 = sm.key[i0], e1 = sm.key[i1];

#pragma unroll
    for (int k = 2; k <= 128; k <<= 1) {                 // in-register stages
      for (int jj = k >> 1; jj > 0; jj >>= 1) {
        if (jj == 64) {
          bool up = ((i0 & k) == 0);
          if (up ? (e0 > e1) : (e0 < e1)) { unsigned long long t = e0; e0 = e1; e1 = t; }
        } else {
          bool amLow = (lane & jj) == 0;
          bool up0 = ((i0 & k) == 0), up1 = ((i1 & k) == 0);
          unsigned long long o0 = shflx64(e0, jj), o1 = shflx64(e1, jj);
          e0 = (up0 == amLow) ? (e0 < o0 ? e0 : o0) : (e0 > o0 ? e0 : o0);
          e1 = (up1 == amLow) ? (e1 < o1 ? e1 : o1) : (e1 > o1 ? e1 : o1);
        }
      }
    }
    for (int k = 256; k <= NBOX; k <<= 1) {              // j>=128 via LDS, j<=64 in regs
      __syncthreads();
      sm.key[i0] = e0; sm.key[i1] = e1;
      __syncthreads();
      for (int jj = k >> 1; jj >= 128; jj >>= 1) {
        int i = ((tid & ~(jj - 1)) << 1) | (tid & (jj - 1));
        int ixj = i + jj;
        unsigned long long a = sm.key[i], b = sm.key[ixj];
        bool up = ((i & k) == 0);
        if (up ? (a > b) : (a < b)) { sm.key[i] = b; sm.key[ixj] = a; }
        __syncthreads();
      }
      e0 = sm.key[i0]; e1 = sm.key[i1];
#pragma unroll
      for (int jj = 64; jj > 0; jj >>= 1) {
        if (jj == 64) {
          bool up = ((i0 & k) == 0);
          if (up ? (e0 > e1) : (e0 < e1)) { unsigned long long t = e0; e0 = e1; e1 = t; }
        } else {
          bool amLow = (lane & jj) == 0;
          bool up0 = ((i0 & k) == 0), up1 = ((i1 & k) == 0);
          unsigned long long o0 = shflx64(e0, jj), o1 = shflx64(e1, jj);
          e0 = (up0 == amLow) ? (e0 < o0 ? e0 : o0) : (e0 > o0 ? e0 : o0);
          e1 = (up1 == amLow) ? (e1 < o1 ? e1 : o1) : (e1 > o1 ? e1 : o1);
        }
      }
    }

#pragma unroll
    for (int s = 0; s < 2; ++s) {                        // write kept rows; tail stays zero
      int r = s ? i1 : i0;
      unsigned long long kv = s ? e1 : e0;
      if (r < K) {
        unsigned meta = (unsigned)kv;
        int idx = (meta >> 7) & (NBOX - 1);
        int lb = meta & 127;
        const float* rr = det + (ibase + idx) * ROWF;    // original (non-offset) boxes
        float* orow = out + (ibase + r) * 6;
        orow[0] = rr[0]; orow[1] = rr[1]; orow[2] = rr[2]; orow[3] = rr[3];
        orow[4] = __uint_as_float(~(unsigned)(kv >> 32));
        orow[5] = cp_ws[ibase + idx];
        out[(size_t)BATCH * NBOX * 6 + ibase + r] = (float)lb;
        out[(size_t)BATCH * NBOX * 7 + ibase + r] = 1.0f;
      }
    }
  }
}

extern "C" void kernel_launch(void* const* d_in, const int* in_sizes, int n_in,
                              void* d_out, int out_size, void* d_ws, size_t ws_size,
                              hipStream_t stream) {
  const float* det = (const float*)d_in[0];
  float* out = (float*)d_out;
  char* ws = (char*)d_ws;

  int* bar = (int*)(ws + WS_BAR);
  float* s_ws = (float*)(ws + WS_S);
  float* cp_ws = (float*)(ws + WS_CP);
  int* l_ws = (int*)(ws + WS_L);
  unsigned long long* keptc = (unsigned long long*)(ws + WS_KC);
  int* kcls = (int*)(ws + WS_KCLS);

  binit_kernel<<<1, 64, 0, stream>>>(bar);
  fused_kernel<<<NBLK, NTHR, 0, stream>>>(det, out, s_ws, cp_ws, l_ws, keptc, kcls, bar);
}

// Round 9
// 61.739 us; speedup vs baseline: 2.6705x; 2.6705x over previous
//
#include <hip/hip_runtime.h>

#define BATCH 16
#define NBOX  2048
#define NCLS  80
#define ROWF  85
#define CONF_THRF 0.2f
#define NMS_THRF  0.45f
#define CAP   128                 // per-(img,class) candidate/kept cap (tail prob ~1e-40)
#define JOBS  (BATCH*NCLS)        // 1280 per-(img,class) NMS jobs

// ws layout (bytes) — no counters, no zeroing needed anywhere
#define WS_S    0                                  // f32[32768] scores
#define WS_CP   (WS_S  + BATCH*NBOX*4)             // f32[32768] classprob max
#define WS_L    (WS_CP + BATCH*NBOX*4)             // i32[32768] labels
#define WS_KC   (WS_L  + BATCH*NBOX*4)             // u64[1280*CAP] kept keys per (img,class)
#define WS_KCLS (WS_KC + (size_t)JOBS*CAP*8)       // i32[1280] kept counts (always written)

static __device__ inline unsigned long long shflx64(unsigned long long v, int m) {
  int lo = __shfl_xor((int)(unsigned)(v & 0xffffffffull), m, 64);
  int hi = __shfl_xor((int)(unsigned)(v >> 32), m, 64);
  return ((unsigned long long)(unsigned)hi << 32) | (unsigned)lo;
}

// ---- K1: per-row score/argmax (16 lanes/row) + zero output. No atomics. ----
__global__ __launch_bounds__(256) void prep_kernel(const float* __restrict__ det,
                                                   float* __restrict__ s_ws,
                                                   float* __restrict__ cp_ws,
                                                   int* __restrict__ l_ws,
                                                   float* __restrict__ outz) {
  const int tid = threadIdx.x;
  const int lane = tid & 63, wavei = tid >> 6;
  const int sub = lane & 15, grp = lane >> 4;
  const int row = blockIdx.x * 16 + wavei * 4 + grp;      // 2048 blocks x 16 rows

  int gid = blockIdx.x * 256 + tid;                       // zero 1MB out with first 65536 thr
  if (gid < (BATCH * NBOX * 8) / 4)
    ((float4*)outz)[gid] = make_float4(0.f, 0.f, 0.f, 0.f);

  const float* r = det + (size_t)row * ROWF;
  float best = r[5 + sub];
  int bc = sub;
#pragma unroll
  for (int k = 1; k < 5; ++k) {                            // classes sub+16k (<80)
    float v = r[5 + sub + 16 * k];
    if (v > best) { best = v; bc = sub + 16 * k; }         // strict >: first max wins
  }
#pragma unroll
  for (int d = 1; d < 16; d <<= 1) {                       // 16-lane argmax, tie -> min idx
    float ov = __shfl_xor(best, d, 16);
    int oc = __shfl_xor(bc, d, 16);
    if (ov > best || (ov == best && oc < bc)) { best = ov; bc = oc; }
  }
  if (sub == 0) { s_ws[row] = r[4]; cp_ws[row] = best; l_ws[row] = bc; }
}

// ---- K2: 16 jobs/block, one wave per (img,class): ballot-scan + wave sort + greedy NMS ----
// (verbatim phase-2 body of the R8 fused kernel, which passed absmax 0)
__global__ __launch_bounds__(1024) void nms16_kernel(const float* __restrict__ det,
                                                     const float* __restrict__ s_ws,
                                                     const int* __restrict__ l_ws,
                                                     unsigned long long* __restrict__ keptc,
                                                     int* __restrict__ kcls) {
  __shared__ unsigned short cand[16][CAP];                 // per-wave candidate lists (4 KB)
  const int tid = threadIdx.x;
  const int lane = tid & 63, wid = tid >> 6;
  const int j = blockIdx.x * 16 + wid;                     // job id 0..1279
  const int img = j / NCLS, c = j - img * NCLS;
  const size_t ibase = (size_t)img * NBOX;
  const float* sImg = s_ws + ibase;
  const int* lImg = l_ws + ibase;
  unsigned short* mycand = cand[wid];

  int cnt = 0;
  for (int it = 0; it < 32; ++it) {                        // coalesced ballot scan, no atomics
    int i = it * 64 + lane;
    bool match = (sImg[i] > CONF_THRF) && (lImg[i] == c);
    unsigned long long mk = __ballot(match);
    if (match) {
      int rk = cnt + __popcll(mk & ((1ull << lane) - 1ull));
      if (rk < CAP) mycand[rk] = (unsigned short)i;
    }
    cnt += __popcll(mk);
  }
  int m = cnt < CAP ? cnt : CAP;

  // keys: (~score_bits)<<32 | idx -> ascending == (score desc, idx asc); pad all-ones
  unsigned long long e0 = ~0ull, e1 = ~0ull;
  if (lane < m) {
    int n = mycand[lane];
    e0 = ((unsigned long long)(~__float_as_uint(sImg[n])) << 32) | (unsigned)n;
  }
  if (lane + 64 < m) {
    int n = mycand[lane + 64];
    e1 = ((unsigned long long)(~__float_as_uint(sImg[n])) << 32) | (unsigned)n;
  }
  const bool two = (m > 64);
  if (!two) {
#pragma unroll
    for (int k = 2; k <= 64; k <<= 1)
      for (int jj = k >> 1; jj > 0; jj >>= 1) {
        bool amLow = (lane & jj) == 0;
        bool up = ((lane & k) == 0);
        unsigned long long o = shflx64(e0, jj);
        e0 = (up == amLow) ? (e0 < o ? e0 : o) : (e0 > o ? e0 : o);
      }
  } else {
#pragma unroll
    for (int k = 2; k <= 128; k <<= 1)
      for (int jj = k >> 1; jj > 0; jj >>= 1) {
        if (jj == 64) {
          bool up = ((lane & k) == 0);
          if (up ? (e0 > e1) : (e0 < e1)) { unsigned long long t = e0; e0 = e1; e1 = t; }
        } else {
          bool amLow = (lane & jj) == 0;
          bool up0 = ((lane & k) == 0), up1 = (((lane + 64) & k) == 0);
          unsigned long long o0 = shflx64(e0, jj), o1 = shflx64(e1, jj);
          e0 = (up0 == amLow) ? (e0 < o0 ? e0 : o0) : (e0 > o0 ? e0 : o0);
          e1 = (up1 == amLow) ? (e1 < o1 ? e1 : o1) : (e1 > o1 ? e1 : o1);
        }
      }
  }

  const float off = (float)c * 10000.0f;
  bool valid0 = lane < m, valid1 = two && (lane + 64 < m);
  int n0 = (int)((unsigned)e0 & (NBOX - 1));
  int n1 = (int)((unsigned)e1 & (NBOX - 1));
  float x1 = 0, y1 = 0, x2 = 0, y2 = 0, ar = 0;
  if (valid0) {
    const float* rr = det + (ibase + n0) * ROWF;
    x1 = rr[0] + off; y1 = rr[1] + off; x2 = rr[2] + off; y2 = rr[3] + off;
    ar = fmaxf(x2 - x1, 0.0f) * fmaxf(y2 - y1, 0.0f);
  }
  float X1 = 0, Y1 = 0, X2 = 0, Y2 = 0, AR = 0;
  if (valid1) {
    const float* rr = det + (ibase + n1) * ROWF;
    X1 = rr[0] + off; Y1 = rr[1] + off; X2 = rr[2] + off; Y2 = rr[3] + off;
    AR = fmaxf(X2 - X1, 0.0f) * fmaxf(Y2 - Y1, 0.0f);
  }

  unsigned long long keptm0 = 0, und = __ballot(valid0);
  while (und) {
    int i = __ffsll((long long)und) - 1;
    keptm0 |= 1ull << i;
    float kx1 = __shfl(x1, i, 64), ky1 = __shfl(y1, i, 64);
    float kx2 = __shfl(x2, i, 64), ky2 = __shfl(y2, i, 64);
    float kar = __shfl(ar, i, 64);
    float iw = fminf(x2, kx2) - fmaxf(x1, kx1);
    float ih = fminf(y2, ky2) - fmaxf(y1, ky1);
    float inter = fmaxf(iw, 0.0f) * fmaxf(ih, 0.0f);
    float iou = inter / (((kar + ar) - inter) + 1e-7f);    // exact ref op order
    bool sup = (lane > i) && (iou > NMS_THRF);
    und &= ~__ballot(sup);
    und &= ~(1ull << i);
  }
  unsigned long long keptm1 = 0;
  if (two) {
    bool dead = false;
    unsigned long long km = keptm0;
    while (km) {
      int t = __ffsll((long long)km) - 1; km &= km - 1;
      float kx1 = __shfl(x1, t, 64), ky1 = __shfl(y1, t, 64);
      float kx2 = __shfl(x2, t, 64), ky2 = __shfl(y2, t, 64);
      float kar = __shfl(ar, t, 64);
      float iw = fminf(X2, kx2) - fmaxf(X1, kx1);
      float ih = fminf(Y2, ky2) - fmaxf(Y1, ky1);
      float inter = fmaxf(iw, 0.0f) * fmaxf(ih, 0.0f);
      float iou = inter / (((kar + AR) - inter) + 1e-7f);
      dead |= (iou > NMS_THRF);
    }
    unsigned long long und1 = __ballot(valid1 && !dead);
    while (und1) {
      int i = __ffsll((long long)und1) - 1;
      keptm1 |= 1ull << i;
      float kx1 = __shfl(X1, i, 64), ky1 = __shfl(Y1, i, 64);
      float kx2 = __shfl(X2, i, 64), ky2 = __shfl(Y2, i, 64);
      float kar = __shfl(AR, i, 64);
      float iw = fminf(X2, kx2) - fmaxf(X1, kx1);
      float ih = fminf(Y2, ky2) - fmaxf(Y1, ky1);
      float inter = fmaxf(iw, 0.0f) * fmaxf(ih, 0.0f);
      float iou = inter / (((kar + AR) - inter) + 1e-7f);
      bool sup = (lane > i) && (iou > NMS_THRF);
      und1 &= ~__ballot(sup);
      und1 &= ~(1ull << i);
    }
  }

  // kept keys to fixed per-class slots (no atomics); count always written
  unsigned long long* dst = keptc + (size_t)j * CAP;
  if ((keptm0 >> lane) & 1) {
    int rank = __popcll(keptm0 & ((1ull << lane) - 1ull));
    dst[rank] = (e0 & 0xffffffff00000000ull) | (unsigned)((n0 << 7) | c);
  }
  if (two && ((keptm1 >> lane) & 1)) {
    int rank = __popcll(keptm0) + __popcll(keptm1 & ((1ull << lane) - 1ull));
    dst[rank] = (e1 & 0xffffffff00000000ull) | (unsigned)((n1 << 7) | c);
  }
  if (lane == 0) kcls[j] = __popcll(keptm0) + __popcll(keptm1);
}

// ---- K3: per-image gather (prefix scan of kcls) + hybrid reg/LDS bitonic + row writes ----
// (verbatim phase-3 body of the R8 fused kernel, which passed absmax 0)
__global__ __launch_bounds__(1024) void outs_kernel(const float* __restrict__ det,
                                                    const float* __restrict__ cp_ws,
                                                    const unsigned long long* __restrict__ keptc,
                                                    const int* __restrict__ kcls,
                                                    float* __restrict__ out) {
  __shared__ unsigned long long key[NBOX];                 // 16 KB sort scratch
  __shared__ int offL[NCLS];
  __shared__ int KtotS;
  const int img = blockIdx.x;
  const int tid = threadIdx.x;
  const int lane = tid & 63, wid = tid >> 6;
  const size_t ibase = (size_t)img * NBOX;

  for (int t = tid; t < NBOX; t += 1024) key[t] = ~0ull;
  __syncthreads();

  if (wid == 0) {                                          // 80-wide exclusive scan
    int v0 = kcls[img * NCLS + lane];
    int v1 = (lane < NCLS - 64) ? kcls[img * NCLS + 64 + lane] : 0;
    int s0 = v0;
#pragma unroll
    for (int d = 1; d < 64; d <<= 1) { int u = __shfl_up(s0, d, 64); if (lane >= d) s0 += u; }
    int total0 = __shfl(s0, 63, 64);
    int s1 = v1;
#pragma unroll
    for (int d = 1; d < 16; d <<= 1) { int u = __shfl_up(s1, d, 64); if (lane >= d) s1 += u; }
    offL[lane] = s0 - v0;
    if (lane < NCLS - 64) offL[64 + lane] = total0 + s1 - v1;
    if (lane == 15) KtotS = total0 + s1;
  }
  __syncthreads();

  for (int c = wid; c < NCLS; c += 16) {                   // gather per-class kept keys
    int kc = kcls[img * NCLS + c];
    const unsigned long long* src = keptc + (size_t)(img * NCLS + c) * CAP;
    int o = offL[c];
    for (int q = lane; q < kc; q += 64) key[o + q] = src[q];
  }
  __syncthreads();

  const int K = KtotS;
  const int i0 = (wid << 7) + lane, i1 = i0 + 64;
  unsigned long long e0 = key[i0], e1 = key[i1];

#pragma unroll
  for (int k = 2; k <= 128; k <<= 1) {                     // in-register stages
    for (int jj = k >> 1; jj > 0; jj >>= 1) {
      if (jj == 64) {
        bool up = ((i0 & k) == 0);
        if (up ? (e0 > e1) : (e0 < e1)) { unsigned long long t = e0; e0 = e1; e1 = t; }
      } else {
        bool amLow = (lane & jj) == 0;
        bool up0 = ((i0 & k) == 0), up1 = ((i1 & k) == 0);
        unsigned long long o0 = shflx64(e0, jj), o1 = shflx64(e1, jj);
        e0 = (up0 == amLow) ? (e0 < o0 ? e0 : o0) : (e0 > o0 ? e0 : o0);
        e1 = (up1 == amLow) ? (e1 < o1 ? e1 : o1) : (e1 > o1 ? e1 : o1);
      }
    }
  }
  for (int k = 256; k <= NBOX; k <<= 1) {                  // j>=128 via LDS, j<=64 in regs
    __syncthreads();
    key[i0] = e0; key[i1] = e1;
    __syncthreads();
    for (int jj = k >> 1; jj >= 128; jj >>= 1) {
      int i = ((tid & ~(jj - 1)) << 1) | (tid & (jj - 1));
      int ixj = i + jj;
      unsigned long long a = key[i], b = key[ixj];
      bool up = ((i & k) == 0);
      if (up ? (a > b) : (a < b)) { key[i] = b; key[ixj] = a; }
      __syncthreads();
    }
    e0 = key[i0]; e1 = key[i1];
#pragma unroll
    for (int jj = 64; jj > 0; jj >>= 1) {
      if (jj == 64) {
        bool up = ((i0 & k) == 0);
        if (up ? (e0 > e1) : (e0 < e1)) { unsigned long long t = e0; e0 = e1; e1 = t; }
      } else {
        bool amLow = (lane & jj) == 0;
        bool up0 = ((i0 & k) == 0), up1 = ((i1 & k) == 0);
        unsigned long long o0 = shflx64(e0, jj), o1 = shflx64(e1, jj);
        e0 = (up0 == amLow) ? (e0 < o0 ? e0 : o0) : (e0 > o0 ? e0 : o0);
        e1 = (up1 == amLow) ? (e1 < o1 ? e1 : o1) : (e1 > o1 ? e1 : o1);
      }
    }
  }

#pragma unroll
  for (int s = 0; s < 2; ++s) {                            // write kept rows; tail stays zero
    int r = s ? i1 : i0;
    unsigned long long kv = s ? e1 : e0;
    if (r < K) {
      unsigned meta = (unsigned)kv;
      int idx = (meta >> 7) & (NBOX - 1);
      int lb = meta & 127;
      const float* rr = det + (ibase + idx) * ROWF;        // original (non-offset) boxes
      float* orow = out + (ibase + r) * 6;
      orow[0] = rr[0]; orow[1] = rr[1]; orow[2] = rr[2]; orow[3] = rr[3];
      orow[4] = __uint_as_float(~(unsigned)(kv >> 32));
      orow[5] = cp_ws[ibase + idx];
      out[(size_t)BATCH * NBOX * 6 + ibase + r] = (float)lb;
      out[(size_t)BATCH * NBOX * 7 + ibase + r] = 1.0f;
    }
  }
}

extern "C" void kernel_launch(void* const* d_in, const int* in_sizes, int n_in,
                              void* d_out, int out_size, void* d_ws, size_t ws_size,
                              hipStream_t stream) {
  const float* det = (const float*)d_in[0];
  float* out = (float*)d_out;
  char* ws = (char*)d_ws;

  float* s_ws = (float*)(ws + WS_S);
  float* cp_ws = (float*)(ws + WS_CP);
  int* l_ws = (int*)(ws + WS_L);
  unsigned long long* keptc = (unsigned long long*)(ws + WS_KC);
  int* kcls = (int*)(ws + WS_KCLS);

  prep_kernel<<<BATCH * NBOX / 16, 256, 0, stream>>>(det, s_ws, cp_ws, l_ws, out);
  nms16_kernel<<<JOBS / 16, 1024, 0, stream>>>(det, s_ws, l_ws, keptc, kcls);
  outs_kernel<<<BATCH, 1024, 0, stream>>>(det, cp_ws, keptc, kcls, out);
}